// Round 1
// baseline (155.306 us; speedup 1.0000x reference)
//
#include <hip/hip_runtime.h>
#include <cstdint>

typedef unsigned long long u64;

constexpr int S = 160;                 // D = H = W = 160
constexpr int NB = 4;                  // batches
constexpr int WPR = 3;                 // u64 words per W-row (160 bits, top 32 of word2 zero)
constexpr int ROWSTRIDE = WPR * S;     // u64 per d-slice row group: 480
constexpr size_t VOL_WORDS = (size_t)NB * S * ROWSTRIDE;   // 307200 u64 = 2,457,600 B

// bit layout: bits[b][d][w][h]  (bit index along W)
__device__ __forceinline__ size_t widx(int b, int d, int w, int h) {
  return (size_t)(b * S + d) * ROWSTRIDE + w * S + h;
}

// the 9 structuring elements: each is a 3x3 plane; parameterized by (u,v) in {-1,0,1}^2
__device__ __forceinline__ void se_off(int SE, int u, int v, int& di, int& dj, int& dk) {
  switch (SE) {
    case 0: di = u; dj = v; dk = 0;  break;   // P[:, :, 1]
    case 1: di = u; dj = 0; dk = v;  break;   // P[:, 1, :]
    case 2: di = 0; dj = u; dk = v;  break;   // P[1, :, :]
    case 3: di = u; dj = v; dk = v;  break;   // P[:, [012], [012]]
    case 4: di = u; dj = v; dk = -v; break;   // P[:, [012], [210]]
    case 5: di = v; dj = u; dk = v;  break;   // P[[012], :, [012]]
    case 6: di = v; dj = u; dk = -v; break;   // P[[012], :, [210]]
    case 7: di = v; dj = v; dk = u;  break;   // P[[012], [012], :]
    default: di = v; dj = -v; dk = u; break;  // P[[012], [210], :]
  }
}

template <int SE, bool IS_OR>
__device__ __forceinline__ void row_op(const u64* __restrict__ src, u64* __restrict__ dst,
                                       int b, int d, int h) {
  u64 a0, a1, a2;
  if (IS_OR) { a0 = a1 = a2 = 0ull; } else { a0 = a1 = a2 = ~0ull; }
#pragma unroll
  for (int u = -1; u <= 1; ++u) {
#pragma unroll
    for (int v = -1; v <= 1; ++v) {
      int di, dj, dk;
      se_off(SE, u, v, di, dj, dk);
      const int dd = d + di, hh = h + dj;
      u64 r0 = 0, r1 = 0, r2 = 0;
      if (dd >= 0 && dd < S && hh >= 0 && hh < S) {
        const u64* p = src + widx(b, dd, 0, hh);
        r0 = p[0]; r1 = p[S]; r2 = p[2 * S];
      }
      u64 s0, s1, s2;
      if (dk == 0)     { s0 = r0;                       s1 = r1;                       s2 = r2; }
      else if (dk > 0) { s0 = (r0 >> 1) | (r1 << 63);   s1 = (r1 >> 1) | (r2 << 63);   s2 = (r2 >> 1); }
      else             { s0 = (r0 << 1);                s1 = (r1 << 1) | (r0 >> 63);   s2 = (r2 << 1) | (r1 >> 63); }
      if (IS_OR) { a0 |= s0; a1 |= s1; a2 |= s2; }
      else       { a0 &= s0; a1 &= s1; a2 &= s2; }
    }
  }
  a2 &= 0xFFFFFFFFull;   // keep padding bits zero (invariant for shifts)
  u64* q = dst + widx(b, d, 0, h);
  q[0] = a0; q[S] = a1; q[2 * S] = a2;
}

// PH0 = first chain (passes 0..8). even batch: close = dilate(OR) then erode(AND);
// odd batch: open = erode(AND) then dilate(OR).
template <int SE, bool PH0>
__global__ __launch_bounds__(256) void pass_k(const u64* __restrict__ src, u64* __restrict__ dst) {
  const int tid = blockIdx.x * 256 + threadIdx.x;
  const int h = tid % S;
  const int t = tid / S;
  const int d = t % S;
  const int b = t / S;   // uniform per block (25600 rows/batch, 256 | 25600)
  if (((b & 1) == 0) == PH0) row_op<SE, true >(src, dst, b, d, h);
  else                       row_op<SE, false>(src, dst, b, d, h);
}

// one block per (b,d,h) row; 192 threads = 3 waves; wave g packs word g via ballot
__global__ __launch_bounds__(192) void pack_k(const float* __restrict__ aux,
                                              const float* __restrict__ inp,
                                              u64* __restrict__ dst) {
  const int row = blockIdx.x;
  const int h = row % S;
  const int t = row / S;
  const int d = t % S;
  const int b = t / S;
  const int wx = threadIdx.x;
  const size_t base = ((size_t)(b * S + d) * S + h) * (size_t)S;
  bool bit = false;
  if (wx < S) {
    const float a = aux[base + wx];
    if (a < 0.0f) bit = true;
    else if (a == 0.0f) bit = (inp[base + wx] != 0.0f);  // inp only read when aux == 0
  }
  const u64 m = __ballot(bit);
  if ((wx & 63) == 0) dst[widx(b, d, wx >> 6, h)] = m;
}

__global__ __launch_bounds__(192) void unpack_k(const u64* __restrict__ src,
                                                float* __restrict__ out) {
  const int row = blockIdx.x;
  const int h = row % S;
  const int t = row / S;
  const int d = t % S;
  const int b = t / S;
  const int wx = threadIdx.x;
  if (wx >= S) return;
  const u64 word = src[widx(b, d, wx >> 6, h)];
  out[((size_t)(b * S + d) * S + h) * (size_t)S + wx] = (float)((word >> (wx & 63)) & 1ull);
}

extern "C" void kernel_launch(void* const* d_in, const int* in_sizes, int n_in,
                              void* d_out, int out_size, void* d_ws, size_t ws_size,
                              hipStream_t stream) {
  (void)in_sizes; (void)n_in; (void)out_size; (void)ws_size;
  const float* inp = (const float*)d_in[0];
  const float* aux = (const float*)d_in[1];
  float* out = (float*)d_out;

  u64* bufA = (u64*)d_ws;
  u64* bufB = bufA + VOL_WORDS;

  const int ROWS = NB * S * S;           // 102400
  const int PG = ROWS / 256;             // 400 blocks for pass kernels

  pack_k<<<ROWS, 192, 0, stream>>>(aux, inp, bufA);

  u64* cur = bufA;
  u64* nxt = bufB;
  for (int p = 0; p < 18; ++p) {
    const bool ph0 = p < 9;
#define LP(se) do { \
      if (ph0) pass_k<se, true ><<<PG, 256, 0, stream>>>(cur, nxt); \
      else     pass_k<se, false><<<PG, 256, 0, stream>>>(cur, nxt); \
    } while (0)
    switch (p % 9) {
      case 0: LP(0); break;
      case 1: LP(1); break;
      case 2: LP(2); break;
      case 3: LP(3); break;
      case 4: LP(4); break;
      case 5: LP(5); break;
      case 6: LP(6); break;
      case 7: LP(7); break;
      default: LP(8); break;
    }
#undef LP
    u64* tmp = cur; cur = nxt; nxt = tmp;
  }

  unpack_k<<<ROWS, 192, 0, stream>>>(cur, out);
}

// Round 2
// 74.036 us; speedup vs baseline: 2.0977x; 2.0977x over previous
//
#include <hip/hip_runtime.h>
#include <cstdint>

typedef unsigned long long u64;

constexpr int S   = 160;          // D = H = W
constexpr int NB  = 4;            // batches
constexpr int PAD = 8;            // d/h padding (max SE reach per pass = 6)
constexpr int SP  = S + 2 * PAD;  // 176 padded rows
constexpr int WSTR = SP;          // stride between k-words of a row
constexpr int DSTR = 3 * SP;      // stride between d-slices (528)
constexpr size_t BUFW = (size_t)NB * SP * 3 * SP;   // u64 per buffer (371,712)

__device__ __forceinline__ int widx(int b, int dp, int w, int hp) {
  return ((b * SP + dp) * 3 + w) * SP + hp;
}

// ---------------- bit-triple (words w-1, w, w+1) helpers ----------------
struct T3 { u64 lo, mi, hi; };

template <bool OR_> __device__ __forceinline__ u64 rop(u64 a, u64 b) { return OR_ ? (a | b) : (a & b); }
template <bool OR_> __device__ __forceinline__ T3 rop3(T3 a, T3 b) {
  return {rop<OR_>(a.lo, b.lo), rop<OR_>(a.mi, b.mi), rop<OR_>(a.hi, b.hi)};
}
template <int N> __device__ __forceinline__ T3 sl3(T3 a) {   // shift toward +k
  return {a.lo << N, (a.mi << N) | (a.lo >> (64 - N)), (a.hi << N) | (a.mi >> (64 - N))};
}
template <int N> __device__ __forceinline__ T3 sr3(T3 a) {   // shift toward -k
  return {(a.lo >> N) | (a.mi << (64 - N)), (a.mi >> N) | (a.hi << (64 - N)), a.hi >> N};
}
// expand-by-1 along k (OR: dilate span+1, AND: erode span+1)
template <bool OR_> __device__ __forceinline__ T3 e1(T3 a) {
  return rop3<OR_>(rop3<OR_>(a, sl3<1>(a)), sr3<1>(a));
}

__device__ __forceinline__ T3 ldt(const u64* __restrict__ p, bool hl, bool hh) {
  T3 t;
  t.mi = p[0];
  t.lo = hl ? p[-WSTR] : 0ull;   // OOB word == bits outside [0,192) == 0 (zero-pad semantics)
  t.hi = hh ? p[WSTR] : 0ull;
  return t;
}

// ---- P1: jk-plane  =  L_j(9) + L_k(9) + Diamond_jk ----
// mask: |dj|<=4 -> k-span 6 ; |dj|=5 -> 5 ; |dj|=6 -> 4
template <bool OR_>
__device__ __forceinline__ u64 p1_core(const u64* __restrict__ p, bool hl, bool hh) {
  T3 G1 = ldt(p - 4, hl, hh);
#pragma unroll
  for (int dj = -3; dj <= 4; ++dj) G1 = rop3<OR_>(G1, ldt(p + dj, hl, hh));
  T3 G2 = rop3<OR_>(ldt(p - 5, hl, hh), ldt(p + 5, hl, hh));
  T3 G3 = rop3<OR_>(ldt(p - 6, hl, hh), ldt(p + 6, hl, hh));
  T3 e2 = e1<OR_>(e1<OR_>(G1));                       // G1 span 2
  T3 X  = rop3<OR_>(rop3<OR_>(e2, e1<OR_>(G2)), G3);  // spans 2/1/0
  T3 y  = e1<OR_>(X);                                 // +1
  T3 R  = rop3<OR_>(rop3<OR_>(y, sl3<3>(y)), sr3<3>(y));  // +3 contiguous -> 6/5/4
  return R.mi;
}

// ---- P2: ik-plane  =  L_i(9) + Diamond_ik ----
// mask: |di|<=4 -> k-span 2 ; |di|=5 -> 1 ; |di|=6 -> 0
template <bool OR_>
__device__ __forceinline__ u64 p2_core(const u64* __restrict__ p, bool hl, bool hh) {
  T3 G1 = ldt(p - 4 * DSTR, hl, hh);
#pragma unroll
  for (int di = -3; di <= 4; ++di) G1 = rop3<OR_>(G1, ldt(p + di * DSTR, hl, hh));
  T3 G2 = rop3<OR_>(ldt(p - 5 * DSTR, hl, hh), ldt(p + 5 * DSTR, hl, hh));
  T3 G3 = rop3<OR_>(ldt(p - 6 * DSTR, hl, hh), ldt(p + 6 * DSTR, hl, hh));
  T3 X = rop3<OR_>(e1<OR_>(rop3<OR_>(e1<OR_>(G1), G2)), G3);
  return X.mi;
}

// ---- P3: ij-diamond: (0,0),(±1,±1),(±2,0),(0,±2) — no k shifts ----
template <bool OR_>
__device__ __forceinline__ u64 p3_core(const u64* __restrict__ p) {
  u64 a = p[0];
  a = rop<OR_>(a, p[DSTR + 1]);  a = rop<OR_>(a, p[DSTR - 1]);
  a = rop<OR_>(a, p[-DSTR + 1]); a = rop<OR_>(a, p[-DSTR - 1]);
  a = rop<OR_>(a, p[2 * DSTR]);  a = rop<OR_>(a, p[-2 * DSTR]);
  a = rop<OR_>(a, p[2]);         a = rop<OR_>(a, p[-2]);
  return a;
}

// PH0: first chain. even batch: close = dilate(OR) first; odd: open = erode(AND) first.
template <int PASS, bool PH0>
__global__ __launch_bounds__(256) void pass_k(const u64* __restrict__ src, u64* __restrict__ dst) {
  const int tid = blockIdx.x * 256 + threadIdx.x;
  const int h = tid % S;
  const int w = (tid / S) % 3;
  const int d = (tid / (S * 3)) % S;
  const int b = tid / (S * 3 * S);             // uniform per block (76800 = 300*256)
  const bool isor = (((b & 1) == 0) == PH0);
  const int idx = widx(b, d + PAD, w, h + PAD);
  const u64* p = src + idx;
  const bool hl = w > 0, hh = w < 2;
  u64 r;
  if (PASS == 1) r = isor ? p1_core<true>(p, hl, hh) : p1_core<false>(p, hl, hh);
  else if (PASS == 2) r = isor ? p2_core<true>(p, hl, hh) : p2_core<false>(p, hl, hh);
  else r = isor ? p3_core<true>(p) : p3_core<false>(p);
  if (w == 2) r &= 0xFFFFFFFFull;              // keep padding bits (k>=160) zero
  dst[idx] = r;
}

// ---------------- pack: float4 aux -> nibbles in LDS -> u64 words ----------------
__device__ __forceinline__ u64 squash(u64 x) {  // 8 bytes of nibbles -> 32 bits
  x = (x | (x >> 4))  & 0x00FF00FF00FF00FFull;
  x = (x | (x >> 8))  & 0x0000FFFF0000FFFFull;
  x = (x | (x >> 16)) & 0x00000000FFFFFFFFull;
  return x;
}

__global__ __launch_bounds__(320) void pack_k(const float* __restrict__ aux,
                                              const float* __restrict__ inp,
                                              u64* __restrict__ dst) {
  __shared__ unsigned char nib[8][48];
  const int r   = threadIdx.x / 40;   // 8 rows per block
  const int pos = threadIdx.x % 40;   // 4 elements each
  const int row = blockIdx.x * 8 + r;
  const size_t ebase = (size_t)row * S + pos * 4;

  const float4 a = reinterpret_cast<const float4*>(aux)[row * 40 + pos];
  unsigned n = 0;
  if (a.x < 0.0f) n |= 1u; else if (a.x == 0.0f) { if (inp[ebase + 0] != 0.0f) n |= 1u; }
  if (a.y < 0.0f) n |= 2u; else if (a.y == 0.0f) { if (inp[ebase + 1] != 0.0f) n |= 2u; }
  if (a.z < 0.0f) n |= 4u; else if (a.z == 0.0f) { if (inp[ebase + 2] != 0.0f) n |= 4u; }
  if (a.w < 0.0f) n |= 8u; else if (a.w == 0.0f) { if (inp[ebase + 3] != 0.0f) n |= 8u; }
  nib[r][pos] = (unsigned char)n;
  if (threadIdx.x < 64) nib[threadIdx.x >> 3][40 + (threadIdx.x & 7)] = 0;
  __syncthreads();

  if (threadIdx.x < 24) {
    const int rr = threadIdx.x & 7;
    const int w  = threadIdx.x >> 3;
    const u64 x0 = *reinterpret_cast<const u64*>(&nib[rr][w * 16]);
    const u64 x1 = *reinterpret_cast<const u64*>(&nib[rr][w * 16 + 8]);
    const u64 word = squash(x0) | (squash(x1) << 32);
    const int grow = blockIdx.x * 8 + rr;
    const int h = grow % S, d = (grow / S) % S, b = grow / (S * S);
    dst[widx(b, d + PAD, w, h + PAD)] = word;
  }
}

__global__ __launch_bounds__(320) void unpack_k(const u64* __restrict__ src,
                                                float* __restrict__ out) {
  const int r   = threadIdx.x / 40;
  const int pos = threadIdx.x % 40;
  const int row = blockIdx.x * 8 + r;
  const int h = row % S, d = (row / S) % S, b = row / (S * S);
  const u64 word = src[widx(b, d + PAD, pos >> 4, h + PAD)];
  const unsigned nb = (unsigned)((word >> ((pos & 15) * 4)) & 0xFull);
  float4 o;
  o.x = (float)(nb & 1u); o.y = (float)((nb >> 1) & 1u);
  o.z = (float)((nb >> 2) & 1u); o.w = (float)((nb >> 3) & 1u);
  reinterpret_cast<float4*>(out)[row * 40 + pos] = o;
}

extern "C" void kernel_launch(void* const* d_in, const int* in_sizes, int n_in,
                              void* d_out, int out_size, void* d_ws, size_t ws_size,
                              hipStream_t stream) {
  (void)in_sizes; (void)n_in; (void)out_size; (void)ws_size;
  const float* inp = (const float*)d_in[0];
  const float* aux = (const float*)d_in[1];
  float* out = (float*)d_out;

  u64* bufA = (u64*)d_ws;
  u64* bufB = bufA + BUFW;

  // zero both buffers (pads must be 0; ws is poisoned 0xAA before timing)
  hipMemsetAsync(d_ws, 0, 2 * BUFW * sizeof(u64), stream);

  const int ROWS = NB * S * S;            // 102400
  pack_k<<<ROWS / 8, 320, 0, stream>>>(aux, inp, bufA);

  const int PG = NB * S * 3 * S / 256;    // 1200 blocks
  u64 *cur = bufA, *nxt = bufB, *t;
  // chain 1
  pass_k<1, true ><<<PG, 256, 0, stream>>>(cur, nxt); t = cur; cur = nxt; nxt = t;
  pass_k<2, true ><<<PG, 256, 0, stream>>>(cur, nxt); t = cur; cur = nxt; nxt = t;
  pass_k<3, true ><<<PG, 256, 0, stream>>>(cur, nxt); t = cur; cur = nxt; nxt = t;
  // chain 2 (opposite op per batch)
  pass_k<1, false><<<PG, 256, 0, stream>>>(cur, nxt); t = cur; cur = nxt; nxt = t;
  pass_k<2, false><<<PG, 256, 0, stream>>>(cur, nxt); t = cur; cur = nxt; nxt = t;
  pass_k<3, false><<<PG, 256, 0, stream>>>(cur, nxt); t = cur; cur = nxt; nxt = t;

  unpack_k<<<ROWS / 8, 320, 0, stream>>>(cur, out);
}

// Round 3
// 72.563 us; speedup vs baseline: 2.1403x; 1.0203x over previous
//
#include <hip/hip_runtime.h>
#include <cstdint>

typedef unsigned long long u64;

constexpr int S   = 160;          // D = H = W
constexpr int NB  = 4;            // batches
constexpr int PAD = 8;            // d/h padding (max SE reach per pass = 6)
constexpr int SP  = S + 2 * PAD;  // 176 padded rows
constexpr int WSTR = SP;          // stride between k-words of a row
constexpr int DSTR = 3 * SP;      // stride between d-slices (528)
constexpr size_t BUFW = (size_t)NB * SP * 3 * SP;   // u64 per buffer (371,712)

__device__ __forceinline__ int widx(int b, int dp, int w, int hp) {
  return ((b * SP + dp) * 3 + w) * SP + hp;
}

// ---------------- bit-triple (words w-1, w, w+1) helpers ----------------
struct T3 { u64 lo, mi, hi; };

template <bool OR_> __device__ __forceinline__ u64 rop(u64 a, u64 b) { return OR_ ? (a | b) : (a & b); }
template <bool OR_> __device__ __forceinline__ T3 rop3(T3 a, T3 b) {
  return {rop<OR_>(a.lo, b.lo), rop<OR_>(a.mi, b.mi), rop<OR_>(a.hi, b.hi)};
}
template <int N> __device__ __forceinline__ T3 sl3(T3 a) {   // shift toward +k
  return {a.lo << N, (a.mi << N) | (a.lo >> (64 - N)), (a.hi << N) | (a.mi >> (64 - N))};
}
template <int N> __device__ __forceinline__ T3 sr3(T3 a) {   // shift toward -k
  return {(a.lo >> N) | (a.mi << (64 - N)), (a.mi >> N) | (a.hi << (64 - N)), a.hi >> N};
}
// expand-by-1 along k (OR: dilate span+1, AND: erode span+1)
template <bool OR_> __device__ __forceinline__ T3 e1(T3 a) {
  return rop3<OR_>(rop3<OR_>(a, sl3<1>(a)), sr3<1>(a));
}

__device__ __forceinline__ T3 ldt(const u64* __restrict__ p, bool hl, bool hh) {
  T3 t;
  t.mi = p[0];
  t.lo = hl ? p[-WSTR] : 0ull;   // OOB word == bits outside [0,192) == 0 (zero-pad semantics)
  t.hi = hh ? p[WSTR] : 0ull;
  return t;
}

// ---- P1: jk-plane  =  L_j(9) + L_k(9) + Diamond_jk ----
// mask: |dj|<=4 -> k-span 6 ; |dj|=5 -> 5 ; |dj|=6 -> 4
template <bool OR_>
__device__ __forceinline__ u64 p1_core(const u64* __restrict__ p, bool hl, bool hh) {
  T3 G1 = ldt(p - 4, hl, hh);
#pragma unroll
  for (int dj = -3; dj <= 4; ++dj) G1 = rop3<OR_>(G1, ldt(p + dj, hl, hh));
  T3 G2 = rop3<OR_>(ldt(p - 5, hl, hh), ldt(p + 5, hl, hh));
  T3 G3 = rop3<OR_>(ldt(p - 6, hl, hh), ldt(p + 6, hl, hh));
  T3 e2 = e1<OR_>(e1<OR_>(G1));                       // G1 span 2
  T3 X  = rop3<OR_>(rop3<OR_>(e2, e1<OR_>(G2)), G3);  // spans 2/1/0
  T3 y  = e1<OR_>(X);                                 // +1
  T3 R  = rop3<OR_>(rop3<OR_>(y, sl3<3>(y)), sr3<3>(y));  // +3 contiguous -> 6/5/4
  return R.mi;
}

// ---- P2: ik-plane  =  L_i(9) + Diamond_ik ----
// mask: |di|<=4 -> k-span 2 ; |di|=5 -> 1 ; |di|=6 -> 0
template <bool OR_>
__device__ __forceinline__ u64 p2_core(const u64* __restrict__ p, bool hl, bool hh) {
  T3 G1 = ldt(p - 4 * DSTR, hl, hh);
#pragma unroll
  for (int di = -3; di <= 4; ++di) G1 = rop3<OR_>(G1, ldt(p + di * DSTR, hl, hh));
  T3 G2 = rop3<OR_>(ldt(p - 5 * DSTR, hl, hh), ldt(p + 5 * DSTR, hl, hh));
  T3 G3 = rop3<OR_>(ldt(p - 6 * DSTR, hl, hh), ldt(p + 6 * DSTR, hl, hh));
  T3 X = rop3<OR_>(e1<OR_>(rop3<OR_>(e1<OR_>(G1), G2)), G3);
  return X.mi;
}

// ---- P3: ij-diamond: (0,0),(±1,±1),(±2,0),(0,±2) — no k shifts ----
template <bool OR_>
__device__ __forceinline__ u64 p3_core(const u64* __restrict__ p) {
  u64 a = p[0];
  a = rop<OR_>(a, p[DSTR + 1]);  a = rop<OR_>(a, p[DSTR - 1]);
  a = rop<OR_>(a, p[-DSTR + 1]); a = rop<OR_>(a, p[-DSTR - 1]);
  a = rop<OR_>(a, p[2 * DSTR]);  a = rop<OR_>(a, p[-2 * DSTR]);
  a = rop<OR_>(a, p[2]);         a = rop<OR_>(a, p[-2]);
  return a;
}

// PH0: first chain. even batch: close = dilate(OR) first; odd: open = erode(AND) first.
template <int PASS, bool PH0>
__global__ __launch_bounds__(256) void pass_k(const u64* __restrict__ src, u64* __restrict__ dst) {
  const int tid = blockIdx.x * 256 + threadIdx.x;
  const int h = tid % S;
  const int w = (tid / S) % 3;
  const int d = (tid / (S * 3)) % S;
  const int b = tid / (S * 3 * S);             // uniform per block (76800 = 300*256)
  const bool isor = (((b & 1) == 0) == PH0);
  const int idx = widx(b, d + PAD, w, h + PAD);
  const u64* p = src + idx;
  const bool hl = w > 0, hh = w < 2;
  u64 r;
  if (PASS == 1) r = isor ? p1_core<true>(p, hl, hh) : p1_core<false>(p, hl, hh);
  else if (PASS == 2) r = isor ? p2_core<true>(p, hl, hh) : p2_core<false>(p, hl, hh);
  else r = isor ? p3_core<true>(p) : p3_core<false>(p);
  if (w == 2) r &= 0xFFFFFFFFull;              // keep padding bits (k>=160) zero
  dst[idx] = r;
}

// zero only the pad halo of both buffers (~1 MB total) — interior is fully
// overwritten by pack_k / pass_k each call, pads are never written by passes.
__global__ __launch_bounds__(256) void zero_pads_k(u64* __restrict__ a, u64* __restrict__ bb) {
  const int tid = blockIdx.x * 256 + threadIdx.x;
  if (tid >= (int)BUFW) return;
  const int hp = tid % SP;
  const int dp = (tid / (SP * 3)) % SP;
  const bool pad = (dp < PAD) | (dp >= S + PAD) | (hp < PAD) | (hp >= S + PAD);
  if (pad) { a[tid] = 0ull; bb[tid] = 0ull; }
}

// ---------------- pack: float4 aux -> nibbles in LDS -> u64 words ----------------
__device__ __forceinline__ u64 squash(u64 x) {  // 8 bytes of nibbles -> 32 bits
  x = (x | (x >> 4))  & 0x00FF00FF00FF00FFull;
  x = (x | (x >> 8))  & 0x0000FFFF0000FFFFull;
  x = (x | (x >> 16)) & 0x00000000FFFFFFFFull;
  return x;
}

__global__ __launch_bounds__(320) void pack_k(const float* __restrict__ aux,
                                              const float* __restrict__ inp,
                                              u64* __restrict__ dst) {
  __shared__ unsigned char nib[8][48];
  const int r   = threadIdx.x / 40;   // 8 rows per block
  const int pos = threadIdx.x % 40;   // 4 elements each
  const int row = blockIdx.x * 8 + r;
  const size_t ebase = (size_t)row * S + pos * 4;

  const float4 a = reinterpret_cast<const float4*>(aux)[row * 40 + pos];
  unsigned n = 0;
  if (a.x < 0.0f) n |= 1u; else if (a.x == 0.0f) { if (inp[ebase + 0] != 0.0f) n |= 1u; }
  if (a.y < 0.0f) n |= 2u; else if (a.y == 0.0f) { if (inp[ebase + 1] != 0.0f) n |= 2u; }
  if (a.z < 0.0f) n |= 4u; else if (a.z == 0.0f) { if (inp[ebase + 2] != 0.0f) n |= 4u; }
  if (a.w < 0.0f) n |= 8u; else if (a.w == 0.0f) { if (inp[ebase + 3] != 0.0f) n |= 8u; }
  nib[r][pos] = (unsigned char)n;
  if (threadIdx.x < 64) nib[threadIdx.x >> 3][40 + (threadIdx.x & 7)] = 0;
  __syncthreads();

  if (threadIdx.x < 24) {
    const int rr = threadIdx.x & 7;
    const int w  = threadIdx.x >> 3;
    const u64 x0 = *reinterpret_cast<const u64*>(&nib[rr][w * 16]);
    const u64 x1 = *reinterpret_cast<const u64*>(&nib[rr][w * 16 + 8]);
    const u64 word = squash(x0) | (squash(x1) << 32);
    const int grow = blockIdx.x * 8 + rr;
    const int h = grow % S, d = (grow / S) % S, b = grow / (S * S);
    dst[widx(b, d + PAD, w, h + PAD)] = word;
  }
}

__global__ __launch_bounds__(320) void unpack_k(const u64* __restrict__ src,
                                                float* __restrict__ out) {
  const int r   = threadIdx.x / 40;
  const int pos = threadIdx.x % 40;
  const int row = blockIdx.x * 8 + r;
  const int h = row % S, d = (row / S) % S, b = row / (S * S);
  const u64 word = src[widx(b, d + PAD, pos >> 4, h + PAD)];
  const unsigned nb = (unsigned)((word >> ((pos & 15) * 4)) & 0xFull);
  float4 o;
  o.x = (float)(nb & 1u); o.y = (float)((nb >> 1) & 1u);
  o.z = (float)((nb >> 2) & 1u); o.w = (float)((nb >> 3) & 1u);
  reinterpret_cast<float4*>(out)[row * 40 + pos] = o;
}

extern "C" void kernel_launch(void* const* d_in, const int* in_sizes, int n_in,
                              void* d_out, int out_size, void* d_ws, size_t ws_size,
                              hipStream_t stream) {
  (void)in_sizes; (void)n_in; (void)out_size; (void)ws_size;
  const float* inp = (const float*)d_in[0];
  const float* aux = (const float*)d_in[1];
  float* out = (float*)d_out;

  u64* bufA = (u64*)d_ws;
  u64* bufB = bufA + BUFW;

  const int ROWS = NB * S * S;            // 102400

  // zero only the pad halo of both buffers (replaces the 40 us rocclr fill)
  const int ZG = ((int)BUFW + 255) / 256; // 1452 blocks
  zero_pads_k<<<ZG, 256, 0, stream>>>(bufA, bufB);

  pack_k<<<ROWS / 8, 320, 0, stream>>>(aux, inp, bufA);

  const int PG = NB * S * 3 * S / 256;    // 1200 blocks
  u64 *cur = bufA, *nxt = bufB, *t;
  // chain 1
  pass_k<1, true ><<<PG, 256, 0, stream>>>(cur, nxt); t = cur; cur = nxt; nxt = t;
  pass_k<2, true ><<<PG, 256, 0, stream>>>(cur, nxt); t = cur; cur = nxt; nxt = t;
  pass_k<3, true ><<<PG, 256, 0, stream>>>(cur, nxt); t = cur; cur = nxt; nxt = t;
  // chain 2 (opposite op per batch)
  pass_k<1, false><<<PG, 256, 0, stream>>>(cur, nxt); t = cur; cur = nxt; nxt = t;
  pass_k<2, false><<<PG, 256, 0, stream>>>(cur, nxt); t = cur; cur = nxt; nxt = t;
  pass_k<3, false><<<PG, 256, 0, stream>>>(cur, nxt); t = cur; cur = nxt; nxt = t;

  unpack_k<<<ROWS / 8, 320, 0, stream>>>(cur, out);
}

// Round 5
// 46.966 us; speedup vs baseline: 3.3068x; 1.5450x over previous
//
#include <hip/hip_runtime.h>
#include <cstdint>

typedef unsigned long long u64;

constexpr int S   = 160;          // D = H = W
constexpr int NB  = 4;            // batches
constexpr int PAD = 8;            // d/h padding in the global bit buffer (chain reach = 8)
constexpr int SP  = S + 2 * PAD;  // 176
constexpr int BUFW = NB * SP * 3 * SP;     // u64 per buffer (371,712)
constexpr int BLKC = 256;                  // chain kernel block size

__device__ __forceinline__ int widx(int b, int dp, int w, int hp) {
  return ((b * SP + dp) * 3 + w) * SP + hp;
}

// ---------------- full-row (3 u64 = 192 bits, k in [0,160)) helpers ----------------
struct R3 { u64 a, b, c; };

template <bool OR_> __device__ __forceinline__ u64 rop(u64 x, u64 y) { return OR_ ? (x | y) : (x & y); }
template <bool OR_> __device__ __forceinline__ R3 rop3(R3 x, R3 y) {
  return {rop<OR_>(x.a, y.a), rop<OR_>(x.b, y.b), rop<OR_>(x.c, y.c)};
}
template <int N> __device__ __forceinline__ R3 sl3(R3 x) {   // toward +k (zeros in)
  return {x.a << N, (x.b << N) | (x.a >> (64 - N)), (x.c << N) | (x.b >> (64 - N))};
}
template <int N> __device__ __forceinline__ R3 sr3(R3 x) {   // toward -k (zeros in)
  return {(x.a >> N) | (x.b << (64 - N)), (x.b >> N) | (x.c << (64 - N)), x.c >> N};
}
template <bool OR_> __device__ __forceinline__ R3 e1(R3 x) { // expand/shrink 1 along k
  return rop3<OR_>(rop3<OR_>(x, sl3<1>(x)), sr3<1>(x));
}
__device__ __forceinline__ R3 ldr(const u64* p) { return {p[0], p[1], p[2]}; }

// ---------------- fused 3-pass chain over an LDS tile ----------------
// Tile: 16x16 (d,h) output rows. IN 32x32 rows (halo 8), T1 32x20, T2 20x20.
// P1 (jk-plane): |dj|<=4 -> k±6 ; |dj|=5 -> ±5 ; |dj|=6 -> ±4
// P2 (ik-plane): |di|<=4 -> k±2 ; |di|=5 -> ±1 ; |di|=6 -> 0
// P3 (ij-diamond): (0,0),(±1,±1),(±2,0),(0,±2), no k reach
template <bool OR_, bool TOOUT>
__device__ void chain_body(const u64* __restrict__ src, u64* __restrict__ dstBits,
                           float* __restrict__ out, int b, int d0, int h0,
                           u64* sIN, u64* sT1, u64* sT2) {
  // load IN: rows d0-8..d0+23, h0-8..h0+23 (padded indices d0+di, h0+hi)
  for (int i = threadIdx.x; i < 32 * 32 * 3; i += BLKC) {
    const int hi = i % 32, w = (i / 32) % 3, di = i / 96;
    sIN[(di * 32 + hi) * 3 + w] = src[widx(b, d0 + di, w, h0 + hi)];
  }
  __syncthreads();

  // P1: outputs d:[-8..23] x h:[-2..17] -> T1[32][20]; input row = hh + 6 + dj
  for (int s = threadIdx.x; s < 32 * 20; s += BLKC) {
    const int dd = s / 20, hh = s % 20;
    const u64* base = sIN + (dd * 32 + hh) * 3;
    R3 G1 = ldr(base + 2 * 3);
#pragma unroll
    for (int r = 3; r <= 10; ++r) G1 = rop3<OR_>(G1, ldr(base + r * 3));
    R3 G2 = rop3<OR_>(ldr(base + 1 * 3), ldr(base + 11 * 3));
    R3 G3 = rop3<OR_>(ldr(base + 0 * 3), ldr(base + 12 * 3));
    R3 X = rop3<OR_>(rop3<OR_>(e1<OR_>(e1<OR_>(G1)), e1<OR_>(G2)), G3);
    R3 y = e1<OR_>(X);
    R3 R = rop3<OR_>(rop3<OR_>(y, sl3<3>(y)), sr3<3>(y));
    R.c &= 0xFFFFFFFFull;
    u64* q = sT1 + s * 3; q[0] = R.a; q[1] = R.b; q[2] = R.c;
  }
  __syncthreads();

  // P2: outputs d:[-2..17] x h:[-2..17] -> T2[20][20]; T1 row = dd + 6 + di
  for (int s = threadIdx.x; s < 20 * 20; s += BLKC) {
    const int dd = s / 20, hh = s % 20;
    const u64* base = sT1 + (dd * 20 + hh) * 3;   // row step = 60 u64
    R3 G1 = ldr(base + 2 * 60);
#pragma unroll
    for (int r = 3; r <= 10; ++r) G1 = rop3<OR_>(G1, ldr(base + r * 60));
    R3 G2 = rop3<OR_>(ldr(base + 1 * 60), ldr(base + 11 * 60));
    R3 G3 = rop3<OR_>(ldr(base + 0 * 60), ldr(base + 12 * 60));
    R3 X = rop3<OR_>(e1<OR_>(rop3<OR_>(e1<OR_>(G1), G2)), G3);
    X.c &= 0xFFFFFFFFull;
    u64* q = sT2 + s * 3; q[0] = X.a; q[1] = X.b; q[2] = X.c;
  }
  __syncthreads();

  // P3: final 16x16; T2 row = (dd+2+di, hh+2+dj)
  {
    const int s = threadIdx.x;           // 256 rows, 1 per thread
    const int dd = s >> 4, hh = s & 15;
    const u64* t2 = sT2 + ((dd + 2) * 20 + (hh + 2)) * 3;
    R3 A = ldr(t2);
    A = rop3<OR_>(A, ldr(t2 + (20 + 1) * 3));  A = rop3<OR_>(A, ldr(t2 + (20 - 1) * 3));
    A = rop3<OR_>(A, ldr(t2 - (20 - 1) * 3));  A = rop3<OR_>(A, ldr(t2 - (20 + 1) * 3));
    A = rop3<OR_>(A, ldr(t2 + 40 * 3));        A = rop3<OR_>(A, ldr(t2 - 40 * 3));
    A = rop3<OR_>(A, ldr(t2 + 2 * 3));         A = rop3<OR_>(A, ldr(t2 - 2 * 3));
    A.c &= 0xFFFFFFFFull;
    if (TOOUT) {
      u64* q = sT1 + s * 3;                // T1 dead after P2 — reuse as OUT tile
      q[0] = A.a; q[1] = A.b; q[2] = A.c;
    } else {
      dstBits[widx(b, d0 + dd + PAD, 0, h0 + hh + PAD)] = A.a;
      dstBits[widx(b, d0 + dd + PAD, 1, h0 + hh + PAD)] = A.b;
      dstBits[widx(b, d0 + dd + PAD, 2, h0 + hh + PAD)] = A.c;
    }
  }
  if (TOOUT) {
    __syncthreads();
    // unpack OUT tile: 256 rows x 40 float4, coalesced
    for (int q = threadIdx.x; q < 16 * 16 * 40; q += BLKC) {
      const int r = q / 40, j = q % 40;
      const int dd = r >> 4, hh = r & 15;
      const u64 word = sT1[r * 3 + (j >> 4)];
      const unsigned nb = (unsigned)((word >> ((j & 15) * 4)) & 0xFull);
      float4 v;
      v.x = (float)(nb & 1u); v.y = (float)((nb >> 1) & 1u);
      v.z = (float)((nb >> 2) & 1u); v.w = (float)((nb >> 3) & 1u);
      const size_t e = ((size_t)((b * S + d0 + dd) * S + h0 + hh)) * S + j * 4;
      *reinterpret_cast<float4*>(out + e) = v;
    }
  }
}

// PH0: first chain (even batch => OR/dilate). TOOUT: emit floats (second chain).
template <bool PH0, bool TOOUT>
__global__ __launch_bounds__(BLKC) void chain_k(const u64* __restrict__ src,
                                                u64* __restrict__ dstBits,
                                                float* __restrict__ out) {
  __shared__ u64 sIN[32 * 32 * 3];   // 24,576 B
  __shared__ u64 sT1[32 * 20 * 3];   // 15,360 B (reused as OUT tile in chain 2)
  __shared__ u64 sT2[20 * 20 * 3];   //  9,600 B
  const int blk = blockIdx.x;
  const int b = blk / 100, tile = blk % 100;
  const int d0 = (tile / 10) * 16, h0 = (tile % 10) * 16;
  const bool isor = (((b & 1) == 0) == PH0);
  if (isor) chain_body<true , TOOUT>(src, dstBits, out, b, d0, h0, sIN, sT1, sT2);
  else      chain_body<false, TOOUT>(src, dstBits, out, b, d0, h0, sIN, sT1, sT2);
}

// ---------------- pack: float4 aux -> nibbles in LDS -> u64 words (+ pad zeroing) ----------------
__device__ __forceinline__ u64 squash(u64 x) {  // 8 bytes of nibbles -> 32 bits
  x = (x | (x >> 4))  & 0x00FF00FF00FF00FFull;
  x = (x | (x >> 8))  & 0x0000FFFF0000FFFFull;
  x = (x | (x >> 16)) & 0x00000000FFFFFFFFull;
  return x;
}

__global__ __launch_bounds__(320) void pack_k(const float* __restrict__ aux,
                                              const float* __restrict__ inp,
                                              u64* __restrict__ dstA,
                                              u64* __restrict__ dstB) {
  // zero the pad halo of both buffers (disjoint from interior writes below)
  {
    const int g = blockIdx.x * 320 + threadIdx.x;
    if (g < BUFW) {
      const int hp = g % SP;
      const int dp = (g / (SP * 3)) % SP;
      if ((dp < PAD) | (dp >= S + PAD) | (hp < PAD) | (hp >= S + PAD)) {
        dstA[g] = 0ull; dstB[g] = 0ull;
      }
    }
  }
  __shared__ unsigned char nib[8][48];
  const int r   = threadIdx.x / 40;   // 8 rows per block
  const int pos = threadIdx.x % 40;   // 4 elements each
  const int row = blockIdx.x * 8 + r;
  const size_t ebase = (size_t)row * S + pos * 4;

  const float4 a = reinterpret_cast<const float4*>(aux)[row * 40 + pos];
  unsigned n = 0;
  if (a.x < 0.0f) n |= 1u; else if (a.x == 0.0f) { if (inp[ebase + 0] != 0.0f) n |= 1u; }
  if (a.y < 0.0f) n |= 2u; else if (a.y == 0.0f) { if (inp[ebase + 1] != 0.0f) n |= 2u; }
  if (a.z < 0.0f) n |= 4u; else if (a.z == 0.0f) { if (inp[ebase + 2] != 0.0f) n |= 4u; }
  if (a.w < 0.0f) n |= 8u; else if (a.w == 0.0f) { if (inp[ebase + 3] != 0.0f) n |= 8u; }
  nib[r][pos] = (unsigned char)n;
  if (threadIdx.x < 64) nib[threadIdx.x >> 3][40 + (threadIdx.x & 7)] = 0;
  __syncthreads();

  if (threadIdx.x < 24) {
    const int rr = threadIdx.x & 7;
    const int w  = threadIdx.x >> 3;
    const u64 x0 = *reinterpret_cast<const u64*>(&nib[rr][w * 16]);
    const u64 x1 = *reinterpret_cast<const u64*>(&nib[rr][w * 16 + 8]);
    const u64 word = squash(x0) | (squash(x1) << 32);
    const int grow = blockIdx.x * 8 + rr;
    const int h = grow % S, d = (grow / S) % S, b = grow / (S * S);
    dstA[widx(b, d + PAD, w, h + PAD)] = word;
  }
}

extern "C" void kernel_launch(void* const* d_in, const int* in_sizes, int n_in,
                              void* d_out, int out_size, void* d_ws, size_t ws_size,
                              hipStream_t stream) {
  (void)in_sizes; (void)n_in; (void)out_size; (void)ws_size;
  const float* inp = (const float*)d_in[0];
  const float* aux = (const float*)d_in[1];
  float* out = (float*)d_out;

  u64* bufA = (u64*)d_ws;
  u64* bufB = bufA + BUFW;

  const int ROWS = NB * S * S;            // 102400
  pack_k<<<ROWS / 8, 320, 0, stream>>>(aux, inp, bufA, bufB);   // 12800 blocks

  const int CG = NB * 100;                // 400 tile blocks
  chain_k<true , false><<<CG, BLKC, 0, stream>>>(bufA, bufB, out);  // chain 1 -> bits
  chain_k<false, true ><<<CG, BLKC, 0, stream>>>(bufB, bufA, out);  // chain 2 -> floats
}

// Round 6
// 41.210 us; speedup vs baseline: 3.7686x; 1.1397x over previous
//
#include <hip/hip_runtime.h>
#include <cstdint>

typedef unsigned long long u64;

constexpr int S   = 160;          // D = H = W
constexpr int NB  = 4;            // batches
constexpr int PAD = 8;            // d/h padding in the global bit buffer (chain reach = 8)
constexpr int SP  = S + 2 * PAD;  // 176
constexpr int BUFW = NB * SP * 3 * SP;     // u64 per buffer (371,712)
constexpr int BLKC = 512;                  // chain kernel block size (8 waves)

__device__ __forceinline__ int widx(int b, int dp, int w, int hp) {
  return ((b * SP + dp) * 3 + w) * SP + hp;
}

// ---------------- full-row (3 u64 = 192 bits, k in [0,160)) helpers ----------------
struct R3 { u64 a, b, c; };

template <bool OR_> __device__ __forceinline__ u64 rop(u64 x, u64 y) { return OR_ ? (x | y) : (x & y); }
template <bool OR_> __device__ __forceinline__ R3 rop3(R3 x, R3 y) {
  return {rop<OR_>(x.a, y.a), rop<OR_>(x.b, y.b), rop<OR_>(x.c, y.c)};
}
template <int N> __device__ __forceinline__ R3 sl3(R3 x) {   // toward +k (zeros in)
  return {x.a << N, (x.b << N) | (x.a >> (64 - N)), (x.c << N) | (x.b >> (64 - N))};
}
template <int N> __device__ __forceinline__ R3 sr3(R3 x) {   // toward -k (zeros in)
  return {(x.a >> N) | (x.b << (64 - N)), (x.b >> N) | (x.c << (64 - N)), x.c >> N};
}
template <bool OR_> __device__ __forceinline__ R3 e1(R3 x) { // expand/shrink 1 along k
  return rop3<OR_>(rop3<OR_>(x, sl3<1>(x)), sr3<1>(x));
}
__device__ __forceinline__ R3 ldr(const u64* p) { return {p[0], p[1], p[2]}; }

// ---------------- fused 3-pass chain over an LDS tile ----------------
// Tile: 16x16 (d,h) output rows. IN 32x32 rows (halo 8), T1 32x20, T2 20x20.
// P1 (jk-plane): |dj|<=4 -> k±6 ; |dj|=5 -> ±5 ; |dj|=6 -> ±4
// P2 (ik-plane): |di|<=4 -> k±2 ; |di|=5 -> ±1 ; |di|=6 -> 0
// P3 (ij-diamond): (0,0),(±1,±1),(±2,0),(0,±2), no k reach
template <bool OR_, bool TOOUT>
__device__ void chain_body(const u64* __restrict__ src, u64* __restrict__ dstBits,
                           float* __restrict__ out, int b, int d0, int h0,
                           u64* sIN, u64* sT1, u64* sT2) {
  // load IN: rows d0-8..d0+23, h0-8..h0+23 (padded indices d0+di, h0+hi)
  for (int i = threadIdx.x; i < 32 * 32 * 3; i += BLKC) {
    const int hi = i % 32, w = (i / 32) % 3, di = i / 96;
    sIN[(di * 32 + hi) * 3 + w] = src[widx(b, d0 + di, w, h0 + hi)];
  }
  __syncthreads();

  // P1: outputs d:[-8..23] x h:[-2..17] -> T1[32][20]; input row = hh + 6 + dj
  for (int s = threadIdx.x; s < 32 * 20; s += BLKC) {
    const int dd = s / 20, hh = s % 20;
    const u64* base = sIN + (dd * 32 + hh) * 3;
    R3 G1 = ldr(base + 2 * 3);
#pragma unroll
    for (int r = 3; r <= 10; ++r) G1 = rop3<OR_>(G1, ldr(base + r * 3));
    R3 G2 = rop3<OR_>(ldr(base + 1 * 3), ldr(base + 11 * 3));
    R3 G3 = rop3<OR_>(ldr(base + 0 * 3), ldr(base + 12 * 3));
    R3 X = rop3<OR_>(rop3<OR_>(e1<OR_>(e1<OR_>(G1)), e1<OR_>(G2)), G3);
    R3 y = e1<OR_>(X);
    R3 R = rop3<OR_>(rop3<OR_>(y, sl3<3>(y)), sr3<3>(y));
    R.c &= 0xFFFFFFFFull;
    u64* q = sT1 + s * 3; q[0] = R.a; q[1] = R.b; q[2] = R.c;
  }
  __syncthreads();

  // P2: outputs d:[-2..17] x h:[-2..17] -> T2[20][20]; T1 row = dd + 6 + di
  for (int s = threadIdx.x; s < 20 * 20; s += BLKC) {
    const int dd = s / 20, hh = s % 20;
    const u64* base = sT1 + (dd * 20 + hh) * 3;   // row step = 60 u64
    R3 G1 = ldr(base + 2 * 60);
#pragma unroll
    for (int r = 3; r <= 10; ++r) G1 = rop3<OR_>(G1, ldr(base + r * 60));
    R3 G2 = rop3<OR_>(ldr(base + 1 * 60), ldr(base + 11 * 60));
    R3 G3 = rop3<OR_>(ldr(base + 0 * 60), ldr(base + 12 * 60));
    R3 X = rop3<OR_>(e1<OR_>(rop3<OR_>(e1<OR_>(G1), G2)), G3);
    X.c &= 0xFFFFFFFFull;
    u64* q = sT2 + s * 3; q[0] = X.a; q[1] = X.b; q[2] = X.c;
  }
  __syncthreads();

  // P3: final 16x16; T2 row = (dd+2+di, hh+2+dj)
  if (threadIdx.x < 256) {
    const int s = threadIdx.x;
    const int dd = s >> 4, hh = s & 15;
    const u64* t2 = sT2 + ((dd + 2) * 20 + (hh + 2)) * 3;
    R3 A = ldr(t2);
    A = rop3<OR_>(A, ldr(t2 + (20 + 1) * 3));  A = rop3<OR_>(A, ldr(t2 + (20 - 1) * 3));
    A = rop3<OR_>(A, ldr(t2 - (20 - 1) * 3));  A = rop3<OR_>(A, ldr(t2 - (20 + 1) * 3));
    A = rop3<OR_>(A, ldr(t2 + 40 * 3));        A = rop3<OR_>(A, ldr(t2 - 40 * 3));
    A = rop3<OR_>(A, ldr(t2 + 2 * 3));         A = rop3<OR_>(A, ldr(t2 - 2 * 3));
    A.c &= 0xFFFFFFFFull;
    if (TOOUT) {
      u64* q = sT1 + s * 3;                // T1 dead after P2 — reuse as OUT tile
      q[0] = A.a; q[1] = A.b; q[2] = A.c;
    } else {
      dstBits[widx(b, d0 + dd + PAD, 0, h0 + hh + PAD)] = A.a;
      dstBits[widx(b, d0 + dd + PAD, 1, h0 + hh + PAD)] = A.b;
      dstBits[widx(b, d0 + dd + PAD, 2, h0 + hh + PAD)] = A.c;
    }
  }
  if (TOOUT) {
    __syncthreads();
    // unpack OUT tile: 256 rows x 40 float4, coalesced
    for (int q = threadIdx.x; q < 16 * 16 * 40; q += BLKC) {
      const int r = q / 40, j = q % 40;
      const int dd = r >> 4, hh = r & 15;
      const u64 word = sT1[r * 3 + (j >> 4)];
      const unsigned nb = (unsigned)((word >> ((j & 15) * 4)) & 0xFull);
      float4 v;
      v.x = (float)(nb & 1u); v.y = (float)((nb >> 1) & 1u);
      v.z = (float)((nb >> 2) & 1u); v.w = (float)((nb >> 3) & 1u);
      const size_t e = ((size_t)((b * S + d0 + dd) * S + h0 + hh)) * S + j * 4;
      *reinterpret_cast<float4*>(out + e) = v;
    }
  }
}

// PH0: first chain (even batch => OR/dilate). TOOUT: emit floats (second chain).
template <bool PH0, bool TOOUT>
__global__ __launch_bounds__(BLKC) void chain_k(const u64* __restrict__ src,
                                                u64* __restrict__ dstBits,
                                                float* __restrict__ out) {
  __shared__ u64 sIN[32 * 32 * 3];   // 24,576 B
  __shared__ u64 sT1[32 * 20 * 3];   // 15,360 B (reused as OUT tile in chain 2)
  __shared__ u64 sT2[20 * 20 * 3];   //  9,600 B
  const int blk = blockIdx.x;
  const int b = blk / 100, tile = blk % 100;
  const int d0 = (tile / 10) * 16, h0 = (tile % 10) * 16;
  const bool isor = (((b & 1) == 0) == PH0);
  if (isor) chain_body<true , TOOUT>(src, dstBits, out, b, d0, h0, sIN, sT1, sT2);
  else      chain_body<false, TOOUT>(src, dstBits, out, b, d0, h0, sIN, sT1, sT2);
}

// ---------------- pack: float4 aux -> nibbles in LDS -> u64 words (+ pad zeroing) ----------------
__device__ __forceinline__ u64 squash(u64 x) {  // 8 bytes of nibbles -> 32 bits
  x = (x | (x >> 4))  & 0x00FF00FF00FF00FFull;
  x = (x | (x >> 8))  & 0x0000FFFF0000FFFFull;
  x = (x | (x >> 16)) & 0x00000000FFFFFFFFull;
  return x;
}

__global__ __launch_bounds__(320) void pack_k(const float* __restrict__ aux,
                                              const float* __restrict__ inp,
                                              u64* __restrict__ dstA,
                                              u64* __restrict__ dstB) {
  // zero the pad halo of both buffers (disjoint from interior writes below)
  {
    const int g = blockIdx.x * 320 + threadIdx.x;
    if (g < BUFW) {
      const int hp = g % SP;
      const int dp = (g / (SP * 3)) % SP;
      if ((dp < PAD) | (dp >= S + PAD) | (hp < PAD) | (hp >= S + PAD)) {
        dstA[g] = 0ull; dstB[g] = 0ull;
      }
    }
  }
  __shared__ unsigned char nib[8][48];
  const int r   = threadIdx.x / 40;   // 8 rows per block
  const int pos = threadIdx.x % 40;   // 4 elements each
  const int row = blockIdx.x * 8 + r;
  const size_t ebase = (size_t)row * S + pos * 4;

  const float4 a = reinterpret_cast<const float4*>(aux)[row * 40 + pos];
  unsigned n = 0;
  if (a.x < 0.0f) n |= 1u; else if (a.x == 0.0f) { if (inp[ebase + 0] != 0.0f) n |= 1u; }
  if (a.y < 0.0f) n |= 2u; else if (a.y == 0.0f) { if (inp[ebase + 1] != 0.0f) n |= 2u; }
  if (a.z < 0.0f) n |= 4u; else if (a.z == 0.0f) { if (inp[ebase + 2] != 0.0f) n |= 4u; }
  if (a.w < 0.0f) n |= 8u; else if (a.w == 0.0f) { if (inp[ebase + 3] != 0.0f) n |= 8u; }
  nib[r][pos] = (unsigned char)n;
  if (threadIdx.x < 64) nib[threadIdx.x >> 3][40 + (threadIdx.x & 7)] = 0;
  __syncthreads();

  if (threadIdx.x < 24) {
    const int rr = threadIdx.x & 7;
    const int w  = threadIdx.x >> 3;
    const u64 x0 = *reinterpret_cast<const u64*>(&nib[rr][w * 16]);
    const u64 x1 = *reinterpret_cast<const u64*>(&nib[rr][w * 16 + 8]);
    const u64 word = squash(x0) | (squash(x1) << 32);
    const int grow = blockIdx.x * 8 + rr;
    const int h = grow % S, d = (grow / S) % S, b = grow / (S * S);
    dstA[widx(b, d + PAD, w, h + PAD)] = word;
  }
}

extern "C" void kernel_launch(void* const* d_in, const int* in_sizes, int n_in,
                              void* d_out, int out_size, void* d_ws, size_t ws_size,
                              hipStream_t stream) {
  (void)in_sizes; (void)n_in; (void)out_size; (void)ws_size;
  const float* inp = (const float*)d_in[0];
  const float* aux = (const float*)d_in[1];
  float* out = (float*)d_out;

  u64* bufA = (u64*)d_ws;
  u64* bufB = bufA + BUFW;

  const int ROWS = NB * S * S;            // 102400
  pack_k<<<ROWS / 8, 320, 0, stream>>>(aux, inp, bufA, bufB);   // 12800 blocks

  const int CG = NB * 100;                // 400 tile blocks
  chain_k<true , false><<<CG, BLKC, 0, stream>>>(bufA, bufB, out);  // chain 1 -> bits
  chain_k<false, true ><<<CG, BLKC, 0, stream>>>(bufB, bufA, out);  // chain 2 -> floats
}